// Round 1
// baseline (266.375 us; speedup 1.0000x reference)
//
#include <hip/hip_runtime.h>
#include <math.h>

constexpr int kB  = 16;
constexpr int kS  = 256;
constexpr int kD  = 1024;
constexpr int kH  = 16;
constexpr float kScale = 0.125f;  // 1/sqrt(64)

using bf16x8  = __attribute__((ext_vector_type(8))) short;
using floatx4 = __attribute__((ext_vector_type(4))) float;
typedef unsigned short u16;

__device__ __forceinline__ u16 f2bf(float x) {
  union { float f; unsigned u; } v; v.f = x;
  unsigned r = v.u + 0x7fffu + ((v.u >> 16) & 1u);
  return (u16)(r >> 16);
}
__device__ __forceinline__ float bf2f(u16 h) {
  union { unsigned u; float f; } v; v.u = ((unsigned)h) << 16;
  return v.f;
}

#define MFMA16(a, b, c) __builtin_amdgcn_mfma_f32_16x16x32_bf16((a), (b), (c), 0, 0, 0)
#define GLL16(gp, lp)                                                        \
  __builtin_amdgcn_global_load_lds(                                          \
      (const __attribute__((address_space(1))) unsigned int*)(gp),           \
      (__attribute__((address_space(3))) unsigned int*)(lp), 16, 0, 0)

// ---------------- pack + table: xA=[x;table], W3=[Wq;Wv;Wk], Wo, b3 ----------
__global__ __launch_bounds__(256) void pack_k(
    const float* __restrict__ x, const float* __restrict__ Wq,
    const float* __restrict__ Wk, const float* __restrict__ Wv,
    const float* __restrict__ Wo,
    const float* __restrict__ bq, const float* __restrict__ bk,
    const float* __restrict__ bv,
    u16* __restrict__ xA, u16* __restrict__ W3b, u16* __restrict__ Wob,
    float* __restrict__ b3) {
  size_t i = ((size_t)blockIdx.x * 256 + threadIdx.x) * 4;
  const size_t NX = (size_t)4194304, NW = (size_t)1048576;
  const size_t BEND = NX + 4 * NW + 3072;
  const float* src;
  u16* dst;
  size_t o;
  if (i < NX) {
    src = x; dst = xA; o = i;
  } else if (i < NX + 3 * NW) {
    size_t j = i - NX;
    int sel = (int)(j >> 20);
    o = j & (NW - 1);
    src = sel == 0 ? Wq : sel == 1 ? Wv : Wk;
    dst = W3b + (size_t)sel * NW;
  } else if (i < NX + 4 * NW) {
    o = i - NX - 3 * NW;
    src = Wo; dst = Wob;
  } else if (i < BEND) {
    size_t j = i - NX - 4 * NW;
    int sel = (int)(j >> 10);
    o = j & 1023;
    src = sel == 0 ? bq : sel == 1 ? bv : bk;
    *reinterpret_cast<float4*>(b3 + j) = *reinterpret_cast<const float4*>(src + o);
    return;
  } else if (i < BEND + 262144) {
    // sinusoid table rows p in [0,256), pos = p-255 -> xA rows 4096..4351
    size_t j = i - BEND;
    int p = (int)(j >> 10);
    int ibase = (int)(j & 1023);
    ushort4 r;
    u16* rr = (u16*)&r;
#pragma unroll
    for (int c = 0; c < 4; ++c) {
      int idx = ibase + c;
      float ex = (float)(2 * (idx / 2)) * (1.0f / 1024.0f);
      float scale = exp2f(ex * -13.287712379549449f);  // 10000^-ex
      float angle = (float)(p - 255) * scale;
      rr[c] = f2bf((idx & 1) ? cosf(angle) : sinf(angle));
    }
    *reinterpret_cast<ushort4*>(xA + NX + j) = r;
    return;
  } else {
    return;
  }
  float4 v = *reinterpret_cast<const float4*>(src + o);
  ushort4 r;
  r.x = f2bf(v.x); r.y = f2bf(v.y); r.z = f2bf(v.z); r.w = f2bf(v.w);
  *reinterpret_cast<ushort4*>(dst + o) = r;
}

// ---------------- rank-16 fold of Wr with u/v: W3b rows 3072..3103, b3 tail ------
__global__ __launch_bounds__(256) void uv_fold_k(
    const float* __restrict__ Wr, const float* __restrict__ br,
    const float* __restrict__ ub, const float* __restrict__ vb,
    u16* __restrict__ W3b, float* __restrict__ b3) {
  int gid = blockIdx.x * 256 + threadIdx.x;  // 32768
  int j = gid >> 10, c = gid & 1023;
  int h = j & 15;
  const float* bvec = (j < 16 ? ub : vb) + h * 64;
  const float* wcol = Wr + (size_t)(h * 64) * 1024 + c;
  float a = 0.f;
#pragma unroll
  for (int d = 0; d < 64; ++d) a += bvec[d] * wcol[(size_t)d * 1024];
  W3b[(size_t)(3072 + j) * 1024 + c] = f2bf(a);
  if (gid < 128) {
    float s = 0.f;
    if (gid < 32) {
      const float* bv2 = (gid < 16 ? ub : vb) + (gid & 15) * 64;
      const float* brp = br + (gid & 15) * 64;
      for (int d = 0; d < 64; ++d) s += bv2[d] * brp[d];
    }
    b3[3072 + gid] = s;
  }
}

// ---------------- legacy 128x128 bf16 MFMA GEMM (used for out-proj) ----------
template <int OUT_MODE>
__global__ __launch_bounds__(256) void gemm_k(
    const u16* __restrict__ A, const u16* __restrict__ W,
    const float* __restrict__ bias, void* __restrict__ Cv,
    int M, int N, int K, float* __restrict__ utb, float* __restrict__ dtb,
    int mTiles, int nTiles) {
  const int xcd = blockIdx.x & 7;
  const int li  = blockIdx.x >> 3;
  const int r0   = (xcd * mTiles) >> 3;
  const int rcnt = (((xcd + 1) * mTiles) >> 3) - r0;
  if (li >= rcnt * nTiles) return;   // uniform early-out (padded grid)
  const int bm = (r0 + li % rcnt) * 128;
  const int bn = (li / rcnt) * 128;

  __shared__ u16 Alds[128 * 64];
  __shared__ u16 Blds[128 * 64];
  const int t = threadIdx.x, w = t >> 6, l = t & 63;
  const int l15 = l & 15, quad = l >> 4;
  const int wm = w >> 1, wn = w & 1;
  const int lrow8 = l >> 3;
  const int kslot = l & 7;

  floatx4 acc[4][4] = {};

  for (int k0 = 0; k0 < K; k0 += 64) {
#pragma unroll
    for (int sg = 0; sg < 4; ++sg) {
      int mrow = sg * 32 + w * 8 + lrow8;
      int gk = (kslot ^ (mrow & 7)) << 3;
      GLL16(A + (size_t)(bm + mrow) * K + k0 + gk, Alds + (sg * 32 + w * 8) * 64);
      GLL16(W + (size_t)(bn + mrow) * K + k0 + gk, Blds + (sg * 32 + w * 8) * 64);
    }
    __syncthreads();
#pragma unroll
    for (int c = 0; c < 2; ++c) {
      bf16x8 af[4], bf[4];
#pragma unroll
      for (int mi = 0; mi < 4; ++mi) {
        int am = wm * 64 + mi * 16 + l15;
        af[mi] = *(const bf16x8*)(Alds + am * 64 + (((c * 4 + quad) ^ (am & 7)) << 3));
      }
#pragma unroll
      for (int ni = 0; ni < 4; ++ni) {
        int an = wn * 64 + ni * 16 + l15;
        bf[ni] = *(const bf16x8*)(Blds + an * 64 + (((c * 4 + quad) ^ (an & 7)) << 3));
      }
#pragma unroll
      for (int mi = 0; mi < 4; ++mi)
#pragma unroll
        for (int ni = 0; ni < 4; ++ni)
          acc[mi][ni] = MFMA16(af[mi], bf[ni], acc[mi][ni]);
    }
    __syncthreads();
  }

#pragma unroll
  for (int ni = 0; ni < 4; ++ni) {
    int col = bn + wn * 64 + ni * 16 + l15;
    float bv = bias[col];
#pragma unroll
    for (int mi = 0; mi < 4; ++mi) {
      int mrow = bm + wm * 64 + mi * 16 + quad * 4;
#pragma unroll
      for (int r = 0; r < 4; ++r) {
        float v = acc[mi][ni][r] + bv;
        int row = mrow + r;
        if (OUT_MODE == 0) {
          ((float*)Cv)[(size_t)row * N + col] = v;
        }
      }
    }
  }
}

// ---------------- 256x256 8-phase bf16 MFMA GEMM (T2+T3+T4+T5) ----------------
// 512 threads = 8 waves (2M x 4N), per-wave output 128x64, BK=64, NT=K/64 tiles.
// LDS: 2 double-buffers x (A 256x64 + B 256x64) bf16 = 128 KiB; XOR-chunk
// swizzle (pre-swizzled global source, swizzled ds_read) as in the 128^2 kernel.
// Per K-tile: 4 phases, each {ds_read sub-block | issue one 16KB half prefetch
// -> s_barrier -> lgkmcnt(0)+sched_barrier -> setprio(1) 16xMFMA setprio(0)
// -> s_barrier}. Counted s_waitcnt vmcnt(2) once per K-tile boundary (never 0
// in steady state). Half-tile stream: halves of tile T issue at
// (T-2,q3),(T-1,q0),(T-1,q1),(T-1,q2); the only same-buffer stage (h0 at q3)
// is issued after q2's closing barrier, i.e. after all waves' reads of that
// region have drained (each wave's lgkmcnt(0) precedes that barrier).
// Epilogue = head-major multi-tensor scatter (OUT_MODE 2 of the old kernel).
#define PHASE_MFMA(aa, bb, mh, nh)                                             \
  do {                                                                         \
    __builtin_amdgcn_s_barrier();                                              \
    asm volatile("s_waitcnt lgkmcnt(0)" ::: "memory");                         \
    __builtin_amdgcn_sched_barrier(0);                                         \
    __builtin_amdgcn_s_setprio(1);                                             \
    _Pragma("unroll") for (int kc = 0; kc < 2; ++kc)                           \
        _Pragma("unroll") for (int i = 0; i < 4; ++i)                          \
            _Pragma("unroll") for (int j = 0; j < 2; ++j)                      \
                acc[(mh) * 4 + i][(nh) * 2 + j] = MFMA16(                      \
                    aa[kc][i], bb[kc][j], acc[(mh) * 4 + i][(nh) * 2 + j]);    \
    __builtin_amdgcn_s_setprio(0);                                             \
  } while (0)

__global__ __launch_bounds__(512, 2) void gemm256_k(
    const u16* __restrict__ A, const u16* __restrict__ W,
    const float* __restrict__ bias, u16* __restrict__ Cv,
    int K, float* __restrict__ utb, float* __restrict__ dtb,
    int mTiles, int nTiles) {
  const int xcd = blockIdx.x & 7;
  const int li  = blockIdx.x >> 3;
  const int r0   = (xcd * mTiles) >> 3;
  const int rcnt = (((xcd + 1) * mTiles) >> 3) - r0;
  if (li >= rcnt * nTiles) return;   // uniform early-out (padded grid)
  const int bm = (r0 + li % rcnt) * 256;
  const int bn = (li / rcnt) * 256;

  __shared__ u16 lds[2 * 32768];     // 128 KiB: [buf][A 256x64 | B 256x64]

  const int t = threadIdx.x, w = t >> 6, l = t & 63;
  const int l15 = l & 15, quad = l >> 4;
  const int wm = w >> 2, wn = w & 3;

  const int NT = K >> 6;
  floatx4 acc[8][4] = {};

  // stage one 16KB half: h0=A rows 0..127, h1=A rows 128..255, h2/h3 = B halves.
  auto stage = [&](int kt, int h) {
    const u16* srcm = (h < 2) ? A : W;
    const int baser = ((h < 2) ? bm : bn) + (h & 1) * 128;
    u16* dst = lds + (kt & 1) * 32768 + h * 8192 + w * 512;
    const int k0 = kt << 6;
#pragma unroll
    for (int j = 0; j < 2; ++j) {
      int sub = w * 8 + (l >> 3) + j * 64;
      int gk = ((l & 7) ^ (sub & 7)) << 3;
      GLL16(srcm + (size_t)(baser + sub) * K + k0 + gk, dst + j * 4096);
    }
  };

  // prologue: tile0 fully + tile1.h0; leave tile1.h0 (2 loads) in flight.
  stage(0, 0); stage(0, 1); stage(0, 2); stage(0, 3);
  stage(1, 0);
  asm volatile("s_waitcnt vmcnt(2)" ::: "memory");
  __builtin_amdgcn_s_barrier();

  for (int kt = 0; kt < NT; ++kt) {
    const u16* LA = lds + (kt & 1) * 32768;
    const u16* LB = LA + 16384;
    bf16x8 a0[2][4], a1[2][4], b0[2][2], b1[2][2];

    // ---- q0: read A-half0 (8) + B-half0 (4); stage (kt+1,h1)
#pragma unroll
    for (int i = 0; i < 4; ++i) {
      int am = wm * 128 + i * 16 + l15;
      const u16* p = LA + am * 64;
      a0[0][i] = *(const bf16x8*)(p + ((quad ^ (am & 7)) << 3));
      a0[1][i] = *(const bf16x8*)(p + (((4 + quad) ^ (am & 7)) << 3));
    }
#pragma unroll
    for (int j = 0; j < 2; ++j) {
      int an = wn * 64 + j * 16 + l15;
      const u16* p = LB + an * 64;
      b0[0][j] = *(const bf16x8*)(p + ((quad ^ (an & 7)) << 3));
      b0[1][j] = *(const bf16x8*)(p + (((4 + quad) ^ (an & 7)) << 3));
    }
    if (kt + 1 < NT) stage(kt + 1, 1);
    PHASE_MFMA(a0, b0, 0, 0);
    __builtin_amdgcn_s_barrier();

    // ---- q1: read B-half1 (4); stage (kt+1,h2)
#pragma unroll
    for (int j = 0; j < 2; ++j) {
      int an = wn * 64 + (2 + j) * 16 + l15;
      const u16* p = LB + an * 64;
      b1[0][j] = *(const bf16x8*)(p + ((quad ^ (an & 7)) << 3));
      b1[1][j] = *(const bf16x8*)(p + (((4 + quad) ^ (an & 7)) << 3));
    }
    if (kt + 1 < NT) stage(kt + 1, 2);
    PHASE_MFMA(a0, b1, 0, 1);
    __builtin_amdgcn_s_barrier();

    // ---- q2: read A-half1 (8); stage (kt+1,h3)
#pragma unroll
    for (int i = 0; i < 4; ++i) {
      int am = wm * 128 + (4 + i) * 16 + l15;
      const u16* p = LA + am * 64;
      a1[0][i] = *(const bf16x8*)(p + ((quad ^ (am & 7)) << 3));
      a1[1][i] = *(const bf16x8*)(p + (((4 + quad) ^ (am & 7)) << 3));
    }
    if (kt + 1 < NT) stage(kt + 1, 3);
    PHASE_MFMA(a1, b0, 1, 0);
    __builtin_amdgcn_s_barrier();

    // ---- q3: stage (kt+2,h0) into the region freed at q2's barrier; MFMA;
    //      K-tile boundary: counted vmcnt (2 loads of (kt+2,h0) may remain).
    if (kt + 2 < NT) stage(kt + 2, 0);
    PHASE_MFMA(a1, b1, 1, 1);
    if (kt + 2 < NT) {
      asm volatile("s_waitcnt vmcnt(2)" ::: "memory");
    } else {
      asm volatile("s_waitcnt vmcnt(0)" ::: "memory");
    }
    __builtin_amdgcn_s_barrier();
  }

  // ---- epilogue: head-major multi-tensor scatter (rows>=4096 are table rows)
#pragma unroll
  for (int ni = 0; ni < 4; ++ni) {
    int col = bn + wn * 64 + ni * 16 + l15;
    float bv = bias[col];
#pragma unroll
    for (int mi = 0; mi < 8; ++mi) {
      int mrow = bm + wm * 128 + mi * 16 + quad * 4;
#pragma unroll
      for (int r = 0; r < 4; ++r) {
        float v = acc[mi][ni][r] + bv;
        int row = mrow + r;
        if (col < 3072) {
          int matsel = col >> 10;        // 0=Q,1=V,2=K
          int hh = (col >> 6) & 15, dd = col & 63;
          if (row < 4096) {
            int bb = row >> 8, ss = row & 255;
            Cv[(size_t)matsel * 4194304 +
               ((size_t)(((bb << 4) + hh) << 8) + ss) * 64 + dd] = f2bf(v);
          } else if (matsel == 2) {      // table @ Wk^T -> RPKh
            int pp = row - 4096;
            Cv[(size_t)3 * 4194304 +
               ((size_t)((hh << 8) + pp)) * 64 + dd] = f2bf(v);
          }
        } else if (col < 3088) {
          if (row < 4096)
            utb[((row >> 8) * 16 + (col - 3072)) * 256 + (row & 255)] = v;
        } else if (col < 3104) {
          if (row >= 4096)
            dtb[(col - 3088) * 256 + (row - 4096)] = v;
        }
        // col >= 3104 (incl. N-pad 3200..3327): discarded
      }
    }
  }
}

// ---------------- fused attention: one block per (b,h), K/V in LDS ----------------
__global__ __launch_bounds__(512, 2) void attn_k(
    const u16* __restrict__ Qh, const u16* __restrict__ Kh,
    const u16* __restrict__ Vh, const u16* __restrict__ RPKh,
    const float* __restrict__ ut, const float* __restrict__ dt,
    u16* __restrict__ vw) {
  __shared__ u16 Klds[256 * 64];     // 32 KB, XOR-swizzled rows
  __shared__ u16 Vt[64][280];        // 35 KB, V transposed
  __shared__ float Sc[32][257];      // scores by z
  __shared__ float Sc2[32][257];     // rel scores by p
  __shared__ float Ut[256], Dt[256], Rinv[32];

  const int bh = blockIdx.x;         // b*16 + h
  const int h = bh & 15;
  const int b = bh >> 4;
  const size_t bh256 = (size_t)bh << 8;

  const int t = threadIdx.x, w = t >> 6, l = t & 63;
  const int l15 = l & 15, quad = l >> 4;

  // ---- staging: K (GLL16), V^T (LDS transpose), Ut, Dt ----
  {
    const int lrow8 = l >> 3, kslot = l & 7;
#pragma unroll
    for (int i = 0; i < 4; ++i) {
      int row = w * 32 + i * 8 + lrow8;
      int gk = (kslot ^ (row & 7)) << 3;
      GLL16(Kh + (bh256 + row) * 64 + gk, Klds + (w * 32 + i * 8) * 64);
    }
  }
  {
    int z = t & 255, dh = t >> 8;    // dh: 0..1 (wave-uniform)
    const u16* gp = Vh + (bh256 + z) * 64 + dh * 32;
    ushort4 vv[8];
#pragma unroll
    for (int i = 0; i < 8; ++i) vv[i] = *(const ushort4*)(gp + i * 4);
#pragma unroll
    for (int i = 0; i < 8; ++i) {
      Vt[dh * 32 + i * 4 + 0][z] = vv[i].x;
      Vt[dh * 32 + i * 4 + 1][z] = vv[i].y;
      Vt[dh * 32 + i * 4 + 2][z] = vv[i].z;
      Vt[dh * 32 + i * 4 + 3][z] = vv[i].w;
    }
  }
  if (t < 256) Ut[t] = ut[bh256 + t];
  else         Dt[t - 256] = dt[((size_t)h << 8) + (t - 256)];
  __syncthreads();

  // ---- loop over 8 s-tiles of 32 rows ----
  for (int st = 0; st < 8; ++st) {
    const int s0 = st * 32;

    bf16x8 qa[2][2];
#pragma unroll
    for (int rt = 0; rt < 2; ++rt) {
      const u16* qp = Qh + (bh256 + s0 + rt * 16 + l15) * 64 + quad * 8;
      qa[rt][0] = *(const bf16x8*)qp;
      qa[rt][1] = *(const bf16x8*)(qp + 32);
    }

    // merged QK (-> Sc) + QR (-> Sc2); tasks round-robin over 8 waves
    {
      int cnt = 0;
#pragma unroll
      for (int rt = 0; rt < 2; ++rt) {
        const int rB = s0 + rt * 16;
        const int nzt = 2 * st + rt + 1;
        for (int zt = 0; zt < nzt; ++zt, ++cnt) {
          if ((cnt & 7) != w) continue;  // wave-uniform
          const int zr = (zt << 4) + l15;
          const u16* krow = Klds + zr * 64;
          bf16x8 kb0 = *(const bf16x8*)(krow + ((quad ^ (zr & 7)) << 3));
          bf16x8 kb1 = *(const bf16x8*)(krow + (((quad + 4) ^ (zr & 7)) << 3));
          floatx4 acc = {};
          acc = MFMA16(qa[rt][0], kb0, acc);
          acc = MFMA16(qa[rt][1], kb1, acc);
          float u = Ut[zr];
#pragma unroll
          for (int r = 0; r < 4; ++r)
            Sc[rt * 16 + quad * 4 + r][zr] = acc[r] + u;
        }
        for (int j = 0; j < nzt; ++j, ++cnt) {
          if ((cnt & 7) != w) continue;
          const int pr = 240 - rB + (j << 4) + l15;
          const u16* rp = RPKh + ((size_t)(h << 8) + pr) * 64 + quad * 8;
          bf16x8 rb0 = *(const bf16x8*)rp;
          bf16x8 rb1 = *(const bf16x8*)(rp + 32);
          floatx4 acc = {};
          acc = MFMA16(qa[rt][0], rb0, acc);
          acc = MFMA16(qa[rt][1], rb1, acc);
          float dv = Dt[pr];
#pragma unroll
          for (int r = 0; r < 4; ++r)
            Sc2[rt * 16 + quad * 4 + r][pr] = acc[r] + dv;
        }
      }
    }
    __syncthreads();

    // softmax: 4 rows/wave, 16 lanes/row; P -> Sc
    {
      const int row = w * 4 + (l >> 4);
      const int c16 = l & 15;
      const int s = s0 + row;
      const int zfill = 32 * (st + 1);
      float m = -1e30f;
      for (int z = c16; z <= s; z += 16)
        m = fmaxf(m, Sc[row][z] + Sc2[row][z - s + 255]);
      m = fmaxf(m, __shfl_xor(m, 1));
      m = fmaxf(m, __shfl_xor(m, 2));
      m = fmaxf(m, __shfl_xor(m, 4));
      m = fmaxf(m, __shfl_xor(m, 8));
      m *= kScale;
      float sum = 0.f;
      for (int z = c16; z < zfill; z += 16) {
        float e = 0.f;
        if (z <= s) {
          e = __expf((Sc[row][z] + Sc2[row][z - s + 255]) * kScale - m);
          sum += e;
        }
        Sc[row][z] = e;
      }
      sum += __shfl_xor(sum, 1);
      sum += __shfl_xor(sum, 2);
      sum += __shfl_xor(sum, 4);
      sum += __shfl_xor(sum, 8);
      if (c16 == 0) Rinv[row] = 1.f / sum;
    }
    __syncthreads();

    // PV: wave = (strip = w>>2, nt = w&3); V from LDS
    {
      const int strip = w >> 2, nt = w & 3;
      const int sB = s0 + strip * 16;
      floatx4 oacc = {};
      for (int kc = 0; kc <= st; ++kc) {
        const float* prow = &Sc[strip * 16 + l15][kc * 32 + quad * 8];
        bf16x8 pa;
        pa[0] = (short)f2bf(prow[0]); pa[1] = (short)f2bf(prow[1]);
        pa[2] = (short)f2bf(prow[2]); pa[3] = (short)f2bf(prow[3]);
        pa[4] = (short)f2bf(prow[4]); pa[5] = (short)f2bf(prow[5]);
        pa[6] = (short)f2bf(prow[6]); pa[7] = (short)f2bf(prow[7]);
        const u16* vp = &Vt[nt * 16 + l15][kc * 32 + quad * 8];
        bf16x8 vbf = *(const bf16x8*)vp;
        oacc = MFMA16(pa, vbf, oacc);
      }
#pragma unroll
      for (int r = 0; r < 4; ++r) {
        float ivr = Rinv[strip * 16 + quad * 4 + r];
        int srow = sB + quad * 4 + r;
        vw[(size_t)(b * 256 + srow) * 1024 + h * 64 + nt * 16 + l15] =
            f2bf(oacc[r] * ivr);
      }
    }
    __syncthreads();
  }
}

extern "C" void kernel_launch(void* const* d_in, const int* in_sizes, int n_in,
                              void* d_out, int out_size, void* d_ws, size_t ws_size,
                              hipStream_t stream) {
  const float* x  = (const float*)d_in[0];
  const float* Wq = (const float*)d_in[1];
  const float* bq = (const float*)d_in[2];
  const float* Wk = (const float*)d_in[3];
  const float* bk = (const float*)d_in[4];
  const float* Wv = (const float*)d_in[5];
  const float* bv = (const float*)d_in[6];
  const float* Wr = (const float*)d_in[7];
  const float* br = (const float*)d_in[8];
  const float* ub = (const float*)d_in[9];
  const float* vb = (const float*)d_in[10];
  const float* Wo = (const float*)d_in[11];
  const float* bo = (const float*)d_in[12];
  float* out = (float*)d_out;

  char* base = (char*)d_ws;
  size_t off = 0;
  auto alloc = [&](size_t bytes) {
    void* p = base + off;
    off += (bytes + 255) & ~(size_t)255;
    return p;
  };

  const size_t MAT = (size_t)4194304;  // 4096*1024
  u16*   xA    = (u16*)alloc((size_t)4352 * 1024 * 2);       // [x ; table]
  u16*   W3b   = (u16*)alloc((size_t)3328 * 1024 * 2);       // [Wq;Wv;Wk;UV;pad to 13 n-tiles]
  u16*   Wob   = (u16*)alloc((size_t)1024 * 1024 * 2);
  float* b3    = (float*)alloc((size_t)3328 * 4);            // [bq;bv;bk;ub.br;vb.br;0;pad]
  u16*   Ph    = (u16*)alloc((3 * MAT + 262144) * 2);        // Qh,Vh,Kh,RPKh
  float* utb   = (float*)alloc((size_t)65536 * 4);
  float* dtb   = (float*)alloc((size_t)4096 * 4);
  u16*   vwb   = (u16*)alloc((size_t)4096 * 1024 * 2);

  u16* Qh   = Ph;
  u16* Vh   = Ph + MAT;
  u16* Kh   = Ph + 2 * MAT;
  u16* RPKh = Ph + 3 * MAT;

  // pack + table: (4194304 + 4194304 + 3072 + 262144)/1024 = 8451 blocks
  pack_k<<<dim3(8451), dim3(256), 0, stream>>>(x, Wq, Wk, Wv, Wo, bq, bk, bv,
                                               xA, W3b, Wob, b3);
  // rank-16 fold of Wr with u/v biases -> W3b rows 3072.., b3 tail
  uv_fold_k<<<dim3(128), dim3(256), 0, stream>>>(Wr, br, ub, vb, W3b, b3);

  // fused Q|V|K + relpos-K + ut/dt projections: 4352 x 3328(pad) x 1024
  // 256^2 8-phase kernel; mTiles=17, nTiles=13; padded grid = 8*ceil(17/8)*13 = 312
  gemm256_k<<<dim3(312), dim3(512), 0, stream>>>(xA, W3b, b3, Ph,
                                                 1024, utb, dtb, 17, 13);

  // fused attention: one block per (b,h)
  attn_k<<<dim3(256), dim3(512), 0, stream>>>(Qh, Kh, Vh, RPKh, utb, dtb, vwb);

  // output projection: 4096 x 1024 x 1024, fp32 out; mTiles=32, nTiles=8 -> 256
  gemm_k<0><<<dim3(256), dim3(256), 0, stream>>>(vwb, Wob, bo, out,
                                                 4096, 1024, 1024, nullptr, nullptr,
                                                 32, 8);
}

// Round 2
// 223.734 us; speedup vs baseline: 1.1906x; 1.1906x over previous
//
#include <hip/hip_runtime.h>
#include <math.h>

constexpr int kB  = 16;
constexpr int kS  = 256;
constexpr int kD  = 1024;
constexpr int kH  = 16;
constexpr float kScale = 0.125f;  // 1/sqrt(64)

using bf16x8  = __attribute__((ext_vector_type(8))) short;
using floatx4 = __attribute__((ext_vector_type(4))) float;
typedef unsigned short u16;

__device__ __forceinline__ u16 f2bf(float x) {
  union { float f; unsigned u; } v; v.f = x;
  unsigned r = v.u + 0x7fffu + ((v.u >> 16) & 1u);
  return (u16)(r >> 16);
}
__device__ __forceinline__ float bf2f(u16 h) {
  union { unsigned u; float f; } v; v.u = ((unsigned)h) << 16;
  return v.f;
}

#define MFMA16(a, b, c) __builtin_amdgcn_mfma_f32_16x16x32_bf16((a), (b), (c), 0, 0, 0)
#define GLL16(gp, lp)                                                        \
  __builtin_amdgcn_global_load_lds(                                          \
      (const __attribute__((address_space(1))) unsigned int*)(gp),           \
      (__attribute__((address_space(3))) unsigned int*)(lp), 16, 0, 0)

// ---------------- pack + table: xA=[x;table], W3=[Wq;Wv;Wk], Wo, b3 ----------
__global__ __launch_bounds__(256) void pack_k(
    const float* __restrict__ x, const float* __restrict__ Wq,
    const float* __restrict__ Wk, const float* __restrict__ Wv,
    const float* __restrict__ Wo,
    const float* __restrict__ bq, const float* __restrict__ bk,
    const float* __restrict__ bv,
    u16* __restrict__ xA, u16* __restrict__ W3b, u16* __restrict__ Wob,
    float* __restrict__ b3) {
  size_t i = ((size_t)blockIdx.x * 256 + threadIdx.x) * 4;
  const size_t NX = (size_t)4194304, NW = (size_t)1048576;
  const size_t BEND = NX + 4 * NW + 3072;
  const float* src;
  u16* dst;
  size_t o;
  if (i < NX) {
    src = x; dst = xA; o = i;
  } else if (i < NX + 3 * NW) {
    size_t j = i - NX;
    int sel = (int)(j >> 20);
    o = j & (NW - 1);
    src = sel == 0 ? Wq : sel == 1 ? Wv : Wk;
    dst = W3b + (size_t)sel * NW;
  } else if (i < NX + 4 * NW) {
    o = i - NX - 3 * NW;
    src = Wo; dst = Wob;
  } else if (i < BEND) {
    size_t j = i - NX - 4 * NW;
    int sel = (int)(j >> 10);
    o = j & 1023;
    src = sel == 0 ? bq : sel == 1 ? bv : bk;
    *reinterpret_cast<float4*>(b3 + j) = *reinterpret_cast<const float4*>(src + o);
    return;
  } else if (i < BEND + 262144) {
    // sinusoid table rows p in [0,256), pos = p-255 -> xA rows 4096..4351
    size_t j = i - BEND;
    int p = (int)(j >> 10);
    int ibase = (int)(j & 1023);
    ushort4 r;
    u16* rr = (u16*)&r;
#pragma unroll
    for (int c = 0; c < 4; ++c) {
      int idx = ibase + c;
      float ex = (float)(2 * (idx / 2)) * (1.0f / 1024.0f);
      float scale = exp2f(ex * -13.287712379549449f);  // 10000^-ex
      float angle = (float)(p - 255) * scale;
      rr[c] = f2bf((idx & 1) ? cosf(angle) : sinf(angle));
    }
    *reinterpret_cast<ushort4*>(xA + NX + j) = r;
    return;
  } else {
    return;
  }
  float4 v = *reinterpret_cast<const float4*>(src + o);
  ushort4 r;
  r.x = f2bf(v.x); r.y = f2bf(v.y); r.z = f2bf(v.z); r.w = f2bf(v.w);
  *reinterpret_cast<ushort4*>(dst + o) = r;
}

// ---------------- rank-16 fold of Wr with u/v: W3b rows 3072..3103, b3 tail ------
__global__ __launch_bounds__(256) void uv_fold_k(
    const float* __restrict__ Wr, const float* __restrict__ br,
    const float* __restrict__ ub, const float* __restrict__ vb,
    u16* __restrict__ W3b, float* __restrict__ b3) {
  int gid = blockIdx.x * 256 + threadIdx.x;  // 32768
  int j = gid >> 10, c = gid & 1023;
  int h = j & 15;
  const float* bvec = (j < 16 ? ub : vb) + h * 64;
  const float* wcol = Wr + (size_t)(h * 64) * 1024 + c;
  float a = 0.f;
#pragma unroll
  for (int d = 0; d < 64; ++d) a += bvec[d] * wcol[(size_t)d * 1024];
  W3b[(size_t)(3072 + j) * 1024 + c] = f2bf(a);
  if (gid < 128) {
    float s = 0.f;
    if (gid < 32) {
      const float* bv2 = (gid < 16 ? ub : vb) + (gid & 15) * 64;
      const float* brp = br + (gid & 15) * 64;
      for (int d = 0; d < 64; ++d) s += bv2[d] * brp[d];
    }
    b3[3072 + gid] = s;
  }
}

// ---------------- legacy 128x128 bf16 MFMA GEMM (used for out-proj) ----------
template <int OUT_MODE>
__global__ __launch_bounds__(256) void gemm_k(
    const u16* __restrict__ A, const u16* __restrict__ W,
    const float* __restrict__ bias, void* __restrict__ Cv,
    int M, int N, int K, float* __restrict__ utb, float* __restrict__ dtb,
    int mTiles, int nTiles) {
  const int xcd = blockIdx.x & 7;
  const int li  = blockIdx.x >> 3;
  const int r0   = (xcd * mTiles) >> 3;
  const int rcnt = (((xcd + 1) * mTiles) >> 3) - r0;
  if (li >= rcnt * nTiles) return;   // uniform early-out (padded grid)
  const int bm = (r0 + li % rcnt) * 128;
  const int bn = (li / rcnt) * 128;

  __shared__ u16 Alds[128 * 64];
  __shared__ u16 Blds[128 * 64];
  const int t = threadIdx.x, w = t >> 6, l = t & 63;
  const int l15 = l & 15, quad = l >> 4;
  const int wm = w >> 1, wn = w & 1;
  const int lrow8 = l >> 3;
  const int kslot = l & 7;

  floatx4 acc[4][4] = {};

  for (int k0 = 0; k0 < K; k0 += 64) {
#pragma unroll
    for (int sg = 0; sg < 4; ++sg) {
      int mrow = sg * 32 + w * 8 + lrow8;
      int gk = (kslot ^ (mrow & 7)) << 3;
      GLL16(A + (size_t)(bm + mrow) * K + k0 + gk, Alds + (sg * 32 + w * 8) * 64);
      GLL16(W + (size_t)(bn + mrow) * K + k0 + gk, Blds + (sg * 32 + w * 8) * 64);
    }
    __syncthreads();
#pragma unroll
    for (int c = 0; c < 2; ++c) {
      bf16x8 af[4], bf[4];
#pragma unroll
      for (int mi = 0; mi < 4; ++mi) {
        int am = wm * 64 + mi * 16 + l15;
        af[mi] = *(const bf16x8*)(Alds + am * 64 + (((c * 4 + quad) ^ (am & 7)) << 3));
      }
#pragma unroll
      for (int ni = 0; ni < 4; ++ni) {
        int an = wn * 64 + ni * 16 + l15;
        bf[ni] = *(const bf16x8*)(Blds + an * 64 + (((c * 4 + quad) ^ (an & 7)) << 3));
      }
#pragma unroll
      for (int mi = 0; mi < 4; ++mi)
#pragma unroll
        for (int ni = 0; ni < 4; ++ni)
          acc[mi][ni] = MFMA16(af[mi], bf[ni], acc[mi][ni]);
    }
    __syncthreads();
  }

#pragma unroll
  for (int ni = 0; ni < 4; ++ni) {
    int col = bn + wn * 64 + ni * 16 + l15;
    float bv = bias[col];
#pragma unroll
    for (int mi = 0; mi < 4; ++mi) {
      int mrow = bm + wm * 64 + mi * 16 + quad * 4;
#pragma unroll
      for (int r = 0; r < 4; ++r) {
        float v = acc[mi][ni][r] + bv;
        int row = mrow + r;
        if (OUT_MODE == 0) {
          ((float*)Cv)[(size_t)row * N + col] = v;
        }
      }
    }
  }
}

// ---------------- 256x256 8-phase bf16 MFMA GEMM (T2+T3+T4+T5) ----------------
// 512 threads = 8 waves (2M x 4N), per-wave output 128x64, BK=64, NT=K/64 tiles.
// LDS: 2 double-buffers x (A 256x64 + B 256x64) bf16 = 128 KiB; XOR-chunk
// swizzle (pre-swizzled global source, swizzled ds_read).
//
// m201-faithful deep stage stream. Region-free points within tile t
// (buf = t&1):  B halves (h2,h3) read at q0 (b0) and q1 (b1) -> free after
// q1's closing barrier;  A halves (h0,h1) read at q0 (a0) and q2 (a1) ->
// free after q2's closing barrier.  Stage placement:
//   (t+1).h1 @ t.q0   (other buffer, free since end of t-1)
//   (t+2).h2 @ t.q2   (B0 region of current buffer, freed at q1 barrier)
//   (t+2).h3 + (t+2).h0 @ t.q3 (freed at q1/q2 barriers)
// Boundary wait (end of t.q3): s_waitcnt vmcnt(6) -> drains (t+1).h1 and all
// older (i.e. tile t+1 fully resident), leaves (t+2).{h2,h3,h0} = 6 loads in
// flight.  Worst prefetch distance: (t+1).h1 issued t.q0, awaited t.q3-end
// (~3.5 phases); B halves get ~4.5 phases.
// Grid: exactly mTiles*nTiles blocks, bijective XCD swizzle (m204) so every
// XCD gets <=28 blocks (<=32 CUs) -> single round, no straggler XCD.
#define PHASE_MFMA(aa, bb, mh, nh)                                             \
  do {                                                                         \
    __builtin_amdgcn_s_barrier();                                              \
    asm volatile("s_waitcnt lgkmcnt(0)" ::: "memory");                         \
    __builtin_amdgcn_sched_barrier(0);                                         \
    __builtin_amdgcn_s_setprio(1);                                             \
    _Pragma("unroll") for (int kc = 0; kc < 2; ++kc)                           \
        _Pragma("unroll") for (int i = 0; i < 4; ++i)                          \
            _Pragma("unroll") for (int j = 0; j < 2; ++j)                      \
                acc[(mh) * 4 + i][(nh) * 2 + j] = MFMA16(                      \
                    aa[kc][i], bb[kc][j], acc[(mh) * 4 + i][(nh) * 2 + j]);    \
    __builtin_amdgcn_s_setprio(0);                                             \
  } while (0)

__global__ __launch_bounds__(512, 2) void gemm256_k(
    const u16* __restrict__ A, const u16* __restrict__ W,
    const float* __restrict__ bias, u16* __restrict__ Cv,
    int K, float* __restrict__ utb, float* __restrict__ dtb,
    int mTiles, int nTiles) {
  // bijective XCD swizzle (m204): per-XCD contiguous wgid chunk, all chunks
  // within 1 of equal size. bm-major within chunk keeps A slab L2-resident.
  const int nwg = mTiles * nTiles;
  const int qq = nwg >> 3, rr = nwg & 7;
  const int xcd = blockIdx.x & 7;
  const int wgid = (xcd < rr ? xcd * (qq + 1) : rr * (qq + 1) + (xcd - rr) * qq)
                   + (blockIdx.x >> 3);
  const int bm = (wgid / nTiles) * 256;
  const int bn = (wgid % nTiles) * 256;

  __shared__ u16 lds[2 * 32768];     // 128 KiB: [buf][A 256x64 | B 256x64]

  const int t = threadIdx.x, w = t >> 6, l = t & 63;
  const int l15 = l & 15, quad = l >> 4;
  const int wm = w >> 2, wn = w & 3;

  const int NT = K >> 6;
  floatx4 acc[8][4] = {};

  // stage one 16KB half: h0=A rows 0..127, h1=A rows 128..255, h2/h3 = B halves.
  auto stage = [&](int kt, int h) {
    const u16* srcm = (h < 2) ? A : W;
    const int baser = ((h < 2) ? bm : bn) + (h & 1) * 128;
    u16* dst = lds + (kt & 1) * 32768 + h * 8192 + w * 512;
    const int k0 = kt << 6;
#pragma unroll
    for (int j = 0; j < 2; ++j) {
      int sub = w * 8 + (l >> 3) + j * 64;
      int gk = ((l & 7) ^ (sub & 7)) << 3;
      GLL16(srcm + (size_t)(baser + sub) * K + k0 + gk, dst + j * 4096);
    }
  };

  // prologue: tile0 fully (order h2,h3,h0,h1) + tile1 {h2,h3,h0}; vmcnt(6)
  // guarantees tile0, leaves tile1's first 3 halves in flight.
  stage(0, 2); stage(0, 3); stage(0, 0); stage(0, 1);
  stage(1, 2); stage(1, 3); stage(1, 0);
  asm volatile("s_waitcnt vmcnt(6)" ::: "memory");
  __builtin_amdgcn_s_barrier();

  for (int kt = 0; kt < NT; ++kt) {
    const u16* LA = lds + (kt & 1) * 32768;
    const u16* LB = LA + 16384;
    bf16x8 a0[2][4], a1[2][4], b0[2][2], b1[2][2];

    // ---- q0: read A-half(wm) lo (8) + B lo (4); stage (kt+1).h1
#pragma unroll
    for (int i = 0; i < 4; ++i) {
      int am = wm * 128 + i * 16 + l15;
      const u16* p = LA + am * 64;
      a0[0][i] = *(const bf16x8*)(p + ((quad ^ (am & 7)) << 3));
      a0[1][i] = *(const bf16x8*)(p + (((4 + quad) ^ (am & 7)) << 3));
    }
#pragma unroll
    for (int j = 0; j < 2; ++j) {
      int an = wn * 64 + j * 16 + l15;
      const u16* p = LB + an * 64;
      b0[0][j] = *(const bf16x8*)(p + ((quad ^ (an & 7)) << 3));
      b0[1][j] = *(const bf16x8*)(p + (((4 + quad) ^ (an & 7)) << 3));
    }
    if (kt + 1 < NT) stage(kt + 1, 1);
    PHASE_MFMA(a0, b0, 0, 0);
    __builtin_amdgcn_s_barrier();

    // ---- q1: read B hi (4); no stage
#pragma unroll
    for (int j = 0; j < 2; ++j) {
      int an = wn * 64 + (2 + j) * 16 + l15;
      const u16* p = LB + an * 64;
      b1[0][j] = *(const bf16x8*)(p + ((quad ^ (an & 7)) << 3));
      b1[1][j] = *(const bf16x8*)(p + (((4 + quad) ^ (an & 7)) << 3));
    }
    PHASE_MFMA(a0, b1, 0, 1);
    __builtin_amdgcn_s_barrier();
    // after this barrier all B reads of buf[kt&1] are done -> h2/h3 restageable

    // ---- q2: read A-half(wm) hi (8); stage (kt+2).h2 into freed B0 region
#pragma unroll
    for (int i = 0; i < 4; ++i) {
      int am = wm * 128 + (4 + i) * 16 + l15;
      const u16* p = LA + am * 64;
      a1[0][i] = *(const bf16x8*)(p + ((quad ^ (am & 7)) << 3));
      a1[1][i] = *(const bf16x8*)(p + (((4 + quad) ^ (am & 7)) << 3));
    }
    if (kt + 2 < NT) stage(kt + 2, 2);
    PHASE_MFMA(a1, b0, 1, 0);
    __builtin_amdgcn_s_barrier();
    // after this barrier all A reads of buf[kt&1] are done -> h0/h1 restageable

    // ---- q3: stage (kt+2).h3 + (kt+2).h0; MFMA; boundary counted vmcnt
    if (kt + 2 < NT) { stage(kt + 2, 3); stage(kt + 2, 0); }
    PHASE_MFMA(a1, b1, 1, 1);
    if (kt + 2 < NT) {
      asm volatile("s_waitcnt vmcnt(6)" ::: "memory");
    } else {
      asm volatile("s_waitcnt vmcnt(0)" ::: "memory");
    }
    __builtin_amdgcn_s_barrier();
  }

  // ---- epilogue: head-major multi-tensor scatter (rows>=4096 are table rows)
#pragma unroll
  for (int ni = 0; ni < 4; ++ni) {
    int col = bn + wn * 64 + ni * 16 + l15;
    float bv = bias[col];
#pragma unroll
    for (int mi = 0; mi < 8; ++mi) {
      int mrow = bm + wm * 128 + mi * 16 + quad * 4;
#pragma unroll
      for (int r = 0; r < 4; ++r) {
        float v = acc[mi][ni][r] + bv;
        int row = mrow + r;
        if (col < 3072) {
          int matsel = col >> 10;        // 0=Q,1=V,2=K
          int hh = (col >> 6) & 15, dd = col & 63;
          if (row < 4096) {
            int bb = row >> 8, ss = row & 255;
            Cv[(size_t)matsel * 4194304 +
               ((size_t)(((bb << 4) + hh) << 8) + ss) * 64 + dd] = f2bf(v);
          } else if (matsel == 2) {      // table @ Wk^T -> RPKh
            int pp = row - 4096;
            Cv[(size_t)3 * 4194304 +
               ((size_t)((hh << 8) + pp)) * 64 + dd] = f2bf(v);
          }
        } else if (col < 3088) {
          if (row < 4096)
            utb[((row >> 8) * 16 + (col - 3072)) * 256 + (row & 255)] = v;
        } else if (col < 3104) {
          if (row >= 4096)
            dtb[(col - 3088) * 256 + (row - 4096)] = v;
        }
        // col >= 3104 (incl. N-pad 3200..3327): discarded
      }
    }
  }
}

// ---------------- fused attention: one block per (b,h), K/V in LDS ----------------
__global__ __launch_bounds__(512, 2) void attn_k(
    const u16* __restrict__ Qh, const u16* __restrict__ Kh,
    const u16* __restrict__ Vh, const u16* __restrict__ RPKh,
    const float* __restrict__ ut, const float* __restrict__ dt,
    u16* __restrict__ vw) {
  __shared__ u16 Klds[256 * 64];     // 32 KB, XOR-swizzled rows
  __shared__ u16 Vt[64][280];        // 35 KB, V transposed
  __shared__ float Sc[32][257];      // scores by z
  __shared__ float Sc2[32][257];     // rel scores by p
  __shared__ float Ut[256], Dt[256], Rinv[32];

  const int bh = blockIdx.x;         // b*16 + h
  const int h = bh & 15;
  const int b = bh >> 4;
  const size_t bh256 = (size_t)bh << 8;

  const int t = threadIdx.x, w = t >> 6, l = t & 63;
  const int l15 = l & 15, quad = l >> 4;

  // ---- staging: K (GLL16), V^T (LDS transpose), Ut, Dt ----
  {
    const int lrow8 = l >> 3, kslot = l & 7;
#pragma unroll
    for (int i = 0; i < 4; ++i) {
      int row = w * 32 + i * 8 + lrow8;
      int gk = (kslot ^ (row & 7)) << 3;
      GLL16(Kh + (bh256 + row) * 64 + gk, Klds + (w * 32 + i * 8) * 64);
    }
  }
  {
    int z = t & 255, dh = t >> 8;    // dh: 0..1 (wave-uniform)
    const u16* gp = Vh + (bh256 + z) * 64 + dh * 32;
    ushort4 vv[8];
#pragma unroll
    for (int i = 0; i < 8; ++i) vv[i] = *(const ushort4*)(gp + i * 4);
#pragma unroll
    for (int i = 0; i < 8; ++i) {
      Vt[dh * 32 + i * 4 + 0][z] = vv[i].x;
      Vt[dh * 32 + i * 4 + 1][z] = vv[i].y;
      Vt[dh * 32 + i * 4 + 2][z] = vv[i].z;
      Vt[dh * 32 + i * 4 + 3][z] = vv[i].w;
    }
  }
  if (t < 256) Ut[t] = ut[bh256 + t];
  else         Dt[t - 256] = dt[((size_t)h << 8) + (t - 256)];
  __syncthreads();

  // ---- loop over 8 s-tiles of 32 rows ----
  for (int st = 0; st < 8; ++st) {
    const int s0 = st * 32;

    bf16x8 qa[2][2];
#pragma unroll
    for (int rt = 0; rt < 2; ++rt) {
      const u16* qp = Qh + (bh256 + s0 + rt * 16 + l15) * 64 + quad * 8;
      qa[rt][0] = *(const bf16x8*)qp;
      qa[rt][1] = *(const bf16x8*)(qp + 32);
    }

    // merged QK (-> Sc) + QR (-> Sc2); tasks round-robin over 8 waves
    {
      int cnt = 0;
#pragma unroll
      for (int rt = 0; rt < 2; ++rt) {
        const int rB = s0 + rt * 16;
        const int nzt = 2 * st + rt + 1;
        for (int zt = 0; zt < nzt; ++zt, ++cnt) {
          if ((cnt & 7) != w) continue;  // wave-uniform
          const int zr = (zt << 4) + l15;
          const u16* krow = Klds + zr * 64;
          bf16x8 kb0 = *(const bf16x8*)(krow + ((quad ^ (zr & 7)) << 3));
          bf16x8 kb1 = *(const bf16x8*)(krow + (((quad + 4) ^ (zr & 7)) << 3));
          floatx4 acc = {};
          acc = MFMA16(qa[rt][0], kb0, acc);
          acc = MFMA16(qa[rt][1], kb1, acc);
          float u = Ut[zr];
#pragma unroll
          for (int r = 0; r < 4; ++r)
            Sc[rt * 16 + quad * 4 + r][zr] = acc[r] + u;
        }
        for (int j = 0; j < nzt; ++j, ++cnt) {
          if ((cnt & 7) != w) continue;
          const int pr = 240 - rB + (j << 4) + l15;
          const u16* rp = RPKh + ((size_t)(h << 8) + pr) * 64 + quad * 8;
          bf16x8 rb0 = *(const bf16x8*)rp;
          bf16x8 rb1 = *(const bf16x8*)(rp + 32);
          floatx4 acc = {};
          acc = MFMA16(qa[rt][0], rb0, acc);
          acc = MFMA16(qa[rt][1], rb1, acc);
          float dv = Dt[pr];
#pragma unroll
          for (int r = 0; r < 4; ++r)
            Sc2[rt * 16 + quad * 4 + r][pr] = acc[r] + dv;
        }
      }
    }
    __syncthreads();

    // softmax: 4 rows/wave, 16 lanes/row; P -> Sc
    {
      const int row = w * 4 + (l >> 4);
      const int c16 = l & 15;
      const int s = s0 + row;
      const int zfill = 32 * (st + 1);
      float m = -1e30f;
      for (int z = c16; z <= s; z += 16)
        m = fmaxf(m, Sc[row][z] + Sc2[row][z - s + 255]);
      m = fmaxf(m, __shfl_xor(m, 1));
      m = fmaxf(m, __shfl_xor(m, 2));
      m = fmaxf(m, __shfl_xor(m, 4));
      m = fmaxf(m, __shfl_xor(m, 8));
      m *= kScale;
      float sum = 0.f;
      for (int z = c16; z < zfill; z += 16) {
        float e = 0.f;
        if (z <= s) {
          e = __expf((Sc[row][z] + Sc2[row][z - s + 255]) * kScale - m);
          sum += e;
        }
        Sc[row][z] = e;
      }
      sum += __shfl_xor(sum, 1);
      sum += __shfl_xor(sum, 2);
      sum += __shfl_xor(sum, 4);
      sum += __shfl_xor(sum, 8);
      if (c16 == 0) Rinv[row] = 1.f / sum;
    }
    __syncthreads();

    // PV: wave = (strip = w>>2, nt = w&3); V from LDS
    {
      const int strip = w >> 2, nt = w & 3;
      const int sB = s0 + strip * 16;
      floatx4 oacc = {};
      for (int kc = 0; kc <= st; ++kc) {
        const float* prow = &Sc[strip * 16 + l15][kc * 32 + quad * 8];
        bf16x8 pa;
        pa[0] = (short)f2bf(prow[0]); pa[1] = (short)f2bf(prow[1]);
        pa[2] = (short)f2bf(prow[2]); pa[3] = (short)f2bf(prow[3]);
        pa[4] = (short)f2bf(prow[4]); pa[5] = (short)f2bf(prow[5]);
        pa[6] = (short)f2bf(prow[6]); pa[7] = (short)f2bf(prow[7]);
        const u16* vp = &Vt[nt * 16 + l15][kc * 32 + quad * 8];
        bf16x8 vbf = *(const bf16x8*)vp;
        oacc = MFMA16(pa, vbf, oacc);
      }
#pragma unroll
      for (int r = 0; r < 4; ++r) {
        float ivr = Rinv[strip * 16 + quad * 4 + r];
        int srow = sB + quad * 4 + r;
        vw[(size_t)(b * 256 + srow) * 1024 + h * 64 + nt * 16 + l15] =
            f2bf(oacc[r] * ivr);
      }
    }
    __syncthreads();
  }
}

extern "C" void kernel_launch(void* const* d_in, const int* in_sizes, int n_in,
                              void* d_out, int out_size, void* d_ws, size_t ws_size,
                              hipStream_t stream) {
  const float* x  = (const float*)d_in[0];
  const float* Wq = (const float*)d_in[1];
  const float* bq = (const float*)d_in[2];
  const float* Wk = (const float*)d_in[3];
  const float* bk = (const float*)d_in[4];
  const float* Wv = (const float*)d_in[5];
  const float* bv = (const float*)d_in[6];
  const float* Wr = (const float*)d_in[7];
  const float* br = (const float*)d_in[8];
  const float* ub = (const float*)d_in[9];
  const float* vb = (const float*)d_in[10];
  const float* Wo = (const float*)d_in[11];
  const float* bo = (const float*)d_in[12];
  float* out = (float*)d_out;

  char* base = (char*)d_ws;
  size_t off = 0;
  auto alloc = [&](size_t bytes) {
    void* p = base + off;
    off += (bytes + 255) & ~(size_t)255;
    return p;
  };

  const size_t MAT = (size_t)4194304;  // 4096*1024
  u16*   xA    = (u16*)alloc((size_t)4352 * 1024 * 2);       // [x ; table]
  u16*   W3b   = (u16*)alloc((size_t)3328 * 1024 * 2);       // [Wq;Wv;Wk;UV;pad to 13 n-tiles]
  u16*   Wob   = (u16*)alloc((size_t)1024 * 1024 * 2);
  float* b3    = (float*)alloc((size_t)3328 * 4);            // [bq;bv;bk;ub.br;vb.br;0;pad]
  u16*   Ph    = (u16*)alloc((3 * MAT + 262144) * 2);        // Qh,Vh,Kh,RPKh
  float* utb   = (float*)alloc((size_t)65536 * 4);
  float* dtb   = (float*)alloc((size_t)4096 * 4);
  u16*   vwb   = (u16*)alloc((size_t)4096 * 1024 * 2);

  u16* Qh   = Ph;
  u16* Vh   = Ph + MAT;
  u16* Kh   = Ph + 2 * MAT;
  u16* RPKh = Ph + 3 * MAT;

  // pack + table: (4194304 + 4194304 + 3072 + 262144)/1024 = 8451 blocks
  pack_k<<<dim3(8451), dim3(256), 0, stream>>>(x, Wq, Wk, Wv, Wo, bq, bk, bv,
                                               xA, W3b, Wob, b3);
  // rank-16 fold of Wr with u/v biases -> W3b rows 3072.., b3 tail
  uv_fold_k<<<dim3(128), dim3(256), 0, stream>>>(Wr, br, ub, vb, W3b, b3);

  // fused Q|V|K + relpos-K + ut/dt projections: 4352 x 3328(pad) x 1024
  // 256^2 8-phase kernel; mTiles=17, nTiles=13 -> exactly 221 blocks,
  // bijective XCD swizzle (27-28 blocks/XCD, single round per CU).
  gemm256_k<<<dim3(221), dim3(512), 0, stream>>>(xA, W3b, b3, Ph,
                                                 1024, utb, dtb, 17, 13);

  // fused attention: one block per (b,h)
  attn_k<<<dim3(256), dim3(512), 0, stream>>>(Qh, Kh, Vh, RPKh, utb, dtb, vwb);

  // output projection: 4096 x 1024 x 1024, fp32 out; mTiles=32, nTiles=8 -> 256
  gemm_k<0><<<dim3(256), dim3(256), 0, stream>>>(vwb, Wob, bo, out,
                                                 4096, 1024, 1024, nullptr, nullptr,
                                                 32, 8);
}

// Round 4
// 221.061 us; speedup vs baseline: 1.2050x; 1.0121x over previous
//
#include <hip/hip_runtime.h>
#include <math.h>

constexpr int kB  = 16;
constexpr int kS  = 256;
constexpr int kD  = 1024;
constexpr int kH  = 16;
constexpr float kScale = 0.125f;  // 1/sqrt(64)

using bf16x8  = __attribute__((ext_vector_type(8))) short;
using floatx4 = __attribute__((ext_vector_type(4))) float;
typedef unsigned short u16;

__device__ __forceinline__ u16 f2bf(float x) {
  union { float f; unsigned u; } v; v.f = x;
  unsigned r = v.u + 0x7fffu + ((v.u >> 16) & 1u);
  return (u16)(r >> 16);
}
__device__ __forceinline__ float bf2f(u16 h) {
  union { unsigned u; float f; } v; v.u = ((unsigned)h) << 16;
  return v.f;
}

#define MFMA16(a, b, c) __builtin_amdgcn_mfma_f32_16x16x32_bf16((a), (b), (c), 0, 0, 0)
#define GLL16(gp, lp)                                                        \
  __builtin_amdgcn_global_load_lds(                                          \
      (const __attribute__((address_space(1))) unsigned int*)(gp),           \
      (__attribute__((address_space(3))) unsigned int*)(lp), 16, 0, 0)

// ---------------- pack + table: xA=[x;table], W3=[Wq;Wv;Wk], Wo, b3 ----------
__global__ __launch_bounds__(256) void pack_k(
    const float* __restrict__ x, const float* __restrict__ Wq,
    const float* __restrict__ Wk, const float* __restrict__ Wv,
    const float* __restrict__ Wo,
    const float* __restrict__ bq, const float* __restrict__ bk,
    const float* __restrict__ bv,
    u16* __restrict__ xA, u16* __restrict__ W3b, u16* __restrict__ Wob,
    float* __restrict__ b3) {
  size_t i = ((size_t)blockIdx.x * 256 + threadIdx.x) * 4;
  const size_t NX = (size_t)4194304, NW = (size_t)1048576;
  const size_t BEND = NX + 4 * NW + 3072;
  const float* src;
  u16* dst;
  size_t o;
  if (i < NX) {
    src = x; dst = xA; o = i;
  } else if (i < NX + 3 * NW) {
    size_t j = i - NX;
    int sel = (int)(j >> 20);
    o = j & (NW - 1);
    src = sel == 0 ? Wq : sel == 1 ? Wv : Wk;
    dst = W3b + (size_t)sel * NW;
  } else if (i < NX + 4 * NW) {
    o = i - NX - 3 * NW;
    src = Wo; dst = Wob;
  } else if (i < BEND) {
    size_t j = i - NX - 4 * NW;
    int sel = (int)(j >> 10);
    o = j & 1023;
    src = sel == 0 ? bq : sel == 1 ? bv : bk;
    *reinterpret_cast<float4*>(b3 + j) = *reinterpret_cast<const float4*>(src + o);
    return;
  } else if (i < BEND + 262144) {
    // sinusoid table rows p in [0,256), pos = p-255 -> xA rows 4096..4351
    size_t j = i - BEND;
    int p = (int)(j >> 10);
    int ibase = (int)(j & 1023);
    ushort4 r;
    u16* rr = (u16*)&r;
#pragma unroll
    for (int c = 0; c < 4; ++c) {
      int idx = ibase + c;
      float ex = (float)(2 * (idx / 2)) * (1.0f / 1024.0f);
      float scale = exp2f(ex * -13.287712379549449f);  // 10000^-ex
      float angle = (float)(p - 255) * scale;
      rr[c] = f2bf((idx & 1) ? cosf(angle) : sinf(angle));
    }
    *reinterpret_cast<ushort4*>(xA + NX + j) = r;
    return;
  } else {
    return;
  }
  float4 v = *reinterpret_cast<const float4*>(src + o);
  ushort4 r;
  r.x = f2bf(v.x); r.y = f2bf(v.y); r.z = f2bf(v.z); r.w = f2bf(v.w);
  *reinterpret_cast<ushort4*>(dst + o) = r;
}

// ---------------- rank-16 fold of Wr with u/v: W3b rows 3072..3103, b3 tail ------
__global__ __launch_bounds__(256) void uv_fold_k(
    const float* __restrict__ Wr, const float* __restrict__ br,
    const float* __restrict__ ub, const float* __restrict__ vb,
    u16* __restrict__ W3b, float* __restrict__ b3) {
  int gid = blockIdx.x * 256 + threadIdx.x;  // 32768
  int j = gid >> 10, c = gid & 1023;
  int h = j & 15;
  const float* bvec = (j < 16 ? ub : vb) + h * 64;
  const float* wcol = Wr + (size_t)(h * 64) * 1024 + c;
  float a = 0.f;
#pragma unroll
  for (int d = 0; d < 64; ++d) a += bvec[d] * wcol[(size_t)d * 1024];
  W3b[(size_t)(3072 + j) * 1024 + c] = f2bf(a);
  if (gid < 128) {
    float s = 0.f;
    if (gid < 32) {
      const float* bv2 = (gid < 16 ? ub : vb) + (gid & 15) * 64;
      const float* brp = br + (gid & 15) * 64;
      for (int d = 0; d < 64; ++d) s += bv2[d] * brp[d];
    }
    b3[3072 + gid] = s;
  }
}

// ---------------- legacy 128x128 bf16 MFMA GEMM (used for out-proj) ----------
template <int OUT_MODE>
__global__ __launch_bounds__(256) void gemm_k(
    const u16* __restrict__ A, const u16* __restrict__ W,
    const float* __restrict__ bias, void* __restrict__ Cv,
    int M, int N, int K, float* __restrict__ utb, float* __restrict__ dtb,
    int mTiles, int nTiles) {
  const int xcd = blockIdx.x & 7;
  const int li  = blockIdx.x >> 3;
  const int r0   = (xcd * mTiles) >> 3;
  const int rcnt = (((xcd + 1) * mTiles) >> 3) - r0;
  if (li >= rcnt * nTiles) return;   // uniform early-out (padded grid)
  const int bm = (r0 + li % rcnt) * 128;
  const int bn = (li / rcnt) * 128;

  __shared__ u16 Alds[128 * 64];
  __shared__ u16 Blds[128 * 64];
  const int t = threadIdx.x, w = t >> 6, l = t & 63;
  const int l15 = l & 15, quad = l >> 4;
  const int wm = w >> 1, wn = w & 1;
  const int lrow8 = l >> 3;
  const int kslot = l & 7;

  floatx4 acc[4][4] = {};

  for (int k0 = 0; k0 < K; k0 += 64) {
#pragma unroll
    for (int sg = 0; sg < 4; ++sg) {
      int mrow = sg * 32 + w * 8 + lrow8;
      int gk = (kslot ^ (mrow & 7)) << 3;
      GLL16(A + (size_t)(bm + mrow) * K + k0 + gk, Alds + (sg * 32 + w * 8) * 64);
      GLL16(W + (size_t)(bn + mrow) * K + k0 + gk, Blds + (sg * 32 + w * 8) * 64);
    }
    __syncthreads();
#pragma unroll
    for (int c = 0; c < 2; ++c) {
      bf16x8 af[4], bf[4];
#pragma unroll
      for (int mi = 0; mi < 4; ++mi) {
        int am = wm * 64 + mi * 16 + l15;
        af[mi] = *(const bf16x8*)(Alds + am * 64 + (((c * 4 + quad) ^ (am & 7)) << 3));
      }
#pragma unroll
      for (int ni = 0; ni < 4; ++ni) {
        int an = wn * 64 + ni * 16 + l15;
        bf[ni] = *(const bf16x8*)(Blds + an * 64 + (((c * 4 + quad) ^ (an & 7)) << 3));
      }
#pragma unroll
      for (int mi = 0; mi < 4; ++mi)
#pragma unroll
        for (int ni = 0; ni < 4; ++ni)
          acc[mi][ni] = MFMA16(af[mi], bf[ni], acc[mi][ni]);
    }
    __syncthreads();
  }

#pragma unroll
  for (int ni = 0; ni < 4; ++ni) {
    int col = bn + wn * 64 + ni * 16 + l15;
    float bv = bias[col];
#pragma unroll
    for (int mi = 0; mi < 4; ++mi) {
      int mrow = bm + wm * 64 + mi * 16 + quad * 4;
#pragma unroll
      for (int r = 0; r < 4; ++r) {
        float v = acc[mi][ni][r] + bv;
        int row = mrow + r;
        if (OUT_MODE == 0) {
          ((float*)Cv)[(size_t)row * N + col] = v;
        }
      }
    }
  }
}

// ---------------- 256x256 8-phase bf16 MFMA GEMM (T2+T3+T4+T5) ----------------
// 512 threads = 8 waves (2M x 4N), per-wave output 128x64, BK=64, NT=K/64.
// LDS: 2 double-buffers x (A 256x64 + B 256x64) bf16 = 128 KiB; XOR-chunk
// swizzle (pre-swizzled global source, swizzled ds_read).
//
// Software-pipelined ds_reads (each read gets >=1 phase of latency cover):
//   q0-pre: readB(b1);  stage(t+1,h1)        | q0: MFMA(a0,b0)  lgkmcnt(4)
//   q1-pre: readA(a1)                        | q1: MFMA(a0,b1)  lgkmcnt(8)
//   q2-pre: stage(t+2,h2)                    | q2: MFMA(a1,b0)  lgkmcnt(0)
//   q3-pre: stage(t+2,h3+h0); vmcnt(6)       | q3: [read next a0,b0] MFMA(a1,b1)
// Next-tile a0/b0 reads sit AFTER q3's open-barrier: that barrier is the first
// all-wave sync after each wave's vmcnt drain, so all waves' global_load_lds
// writes of tile t+1 have landed (per-wave vmcnt does NOT cover other waves).
// Region-free proof per stage: h1 writes other buffer (reads drained 2 tiles
// ago); h2 overwrites B0 after q1-close (b0 drained at q0-wait, all waves);
// h3/h0 overwrite B1/A0 after q2-close (b1 drained at q1-wait, a0 at q0-wait).
// Epilogue: fp32 LDS bounce (reuses staging LDS, XOR key kills bank
// conflicts) -> coalesced 128B/wave ushort4 stores (kills 2.1x write amp).
#define PHASE_MFMA(aa, bb, mh, nh, LG)                                         \
  do {                                                                         \
    __builtin_amdgcn_s_barrier();                                              \
    asm volatile("s_waitcnt lgkmcnt(" #LG ")" ::: "memory");                   \
    __builtin_amdgcn_sched_barrier(0);                                         \
    __builtin_amdgcn_s_setprio(1);                                             \
    _Pragma("unroll") for (int kc = 0; kc < 2; ++kc)                           \
        _Pragma("unroll") for (int i = 0; i < 4; ++i)                          \
            _Pragma("unroll") for (int j = 0; j < 2; ++j)                      \
                acc[(mh) * 4 + i][(nh) * 2 + j] = MFMA16(                      \
                    aa[kc][i], bb[kc][j], acc[(mh) * 4 + i][(nh) * 2 + j]);    \
    __builtin_amdgcn_s_setprio(0);                                             \
  } while (0)

__global__ __launch_bounds__(512, 2) void gemm256_k(
    const u16* __restrict__ A, const u16* __restrict__ W,
    const float* __restrict__ bias, u16* __restrict__ Cv,
    int K, float* __restrict__ utb, float* __restrict__ dtb,
    int mTiles, int nTiles) {
  // bijective XCD swizzle (m204): per-XCD contiguous wgid chunk; bm-major
  // within chunk keeps the A slab L2-resident.
  const int nwg = mTiles * nTiles;
  const int qq = nwg >> 3, rr8 = nwg & 7;
  const int xcd = blockIdx.x & 7;
  const int wgid = (xcd < rr8 ? xcd * (qq + 1) : rr8 * (qq + 1) + (xcd - rr8) * qq)
                   + (blockIdx.x >> 3);
  const int bm = (wgid / nTiles) * 256;
  const int bn = (wgid % nTiles) * 256;

  __shared__ u16 lds[2 * 32768];     // 128 KiB: [buf][A 256x64 | B 256x64]

  const int t = threadIdx.x, w = t >> 6, l = t & 63;
  const int l15 = l & 15, quad = l >> 4;
  const int wm = w >> 2, wn = w & 3;

  const int NT = K >> 6;
  floatx4 acc[8][4] = {};

  // stage one 16KB half: h0=A rows 0..127, h1=A rows 128..255, h2/h3 = B halves.
  auto stage = [&](int kt, int h) {
    const u16* srcm = (h < 2) ? A : W;
    const int baser = ((h < 2) ? bm : bn) + (h & 1) * 128;
    u16* dst = lds + (kt & 1) * 32768 + h * 8192 + w * 512;
    const int k0 = kt << 6;
#pragma unroll
    for (int j = 0; j < 2; ++j) {
      int sub = w * 8 + (l >> 3) + j * 64;
      int gk = ((l & 7) ^ (sub & 7)) << 3;
      GLL16(srcm + (size_t)(baser + sub) * K + k0 + gk, dst + j * 4096);
    }
  };

  bf16x8 a0[2][4], a1[2][4], b0[2][2], b1[2][2];

  auto readA = [&](bf16x8 (&aa)[2][4], const u16* LA, int hh) {
#pragma unroll
    for (int i = 0; i < 4; ++i) {
      int am = wm * 128 + hh * 64 + i * 16 + l15;
      const u16* p = LA + am * 64;
      aa[0][i] = *(const bf16x8*)(p + ((quad ^ (am & 7)) << 3));
      aa[1][i] = *(const bf16x8*)(p + (((4 + quad) ^ (am & 7)) << 3));
    }
  };
  auto readB = [&](bf16x8 (&bb)[2][2], const u16* LB, int hh) {
#pragma unroll
    for (int j = 0; j < 2; ++j) {
      int an = wn * 64 + hh * 32 + j * 16 + l15;
      const u16* p = LB + an * 64;
      bb[0][j] = *(const bf16x8*)(p + ((quad ^ (an & 7)) << 3));
      bb[1][j] = *(const bf16x8*)(p + (((4 + quad) ^ (an & 7)) << 3));
    }
  };

  // prologue: tile0 fully + tile1 {h2,h3,h0}; vmcnt(6) -> tile0 resident
  // (per-wave); barrier -> all waves' tile0 writes landed; then read a0,b0.
  stage(0, 2); stage(0, 3); stage(0, 0); stage(0, 1);
  stage(1, 2); stage(1, 3); stage(1, 0);
  asm volatile("s_waitcnt vmcnt(6)" ::: "memory");
  __builtin_amdgcn_s_barrier();
  readA(a0, lds, 0);
  readB(b0, lds + 16384, 0);

  for (int kt = 0; kt < NT; ++kt) {
    const u16* LA = lds + (kt & 1) * 32768;
    const u16* LB = LA + 16384;

    // ---- q0: pre: readB(b1); stage(kt+1,h1). MFMA(a0,b0). 12 old reads
    //      (a0,b0) must drain, 4 new (b1) may remain -> lgkmcnt(4).
    readB(b1, LB, 1);
    if (kt + 1 < NT) stage(kt + 1, 1);
    PHASE_MFMA(a0, b0, 0, 0, 4);
    __builtin_amdgcn_s_barrier();

    // ---- q1: pre: readA(a1). MFMA(a0,b1). b1 (4 oldest) must drain,
    //      a1 (8) may remain -> lgkmcnt(8).
    readA(a1, LA, 1);
    PHASE_MFMA(a0, b1, 0, 1, 8);
    __builtin_amdgcn_s_barrier();

    // ---- q2: pre: stage(kt+2,h2) into B0 region (b0 drained at q0-wait,
    //      all waves past q1-close). MFMA(a1,b0). a1 must drain -> 0.
    if (kt + 2 < NT) stage(kt + 2, 2);
    PHASE_MFMA(a1, b0, 1, 0, 0);
    __builtin_amdgcn_s_barrier();

    // ---- q3: pre: stage(kt+2,h3+h0); counted vmcnt (tile kt+1 resident,
    //      (kt+2).{h2,h3,h0}=6 loads stay in flight). Open-barrier then
    //      gives the cross-wave guarantee -> read next tile's a0,b0 inside
    //      the MFMA region (latency hidden under MFMA + 2 barriers + q0-pre).
    if (kt + 2 < NT) {
      stage(kt + 2, 3); stage(kt + 2, 0);
      asm volatile("s_waitcnt vmcnt(6)" ::: "memory");
    } else {
      asm volatile("s_waitcnt vmcnt(0)" ::: "memory");
    }
    __builtin_amdgcn_s_barrier();
    asm volatile("s_waitcnt lgkmcnt(0)" ::: "memory");
    __builtin_amdgcn_sched_barrier(0);
    if (kt + 1 < NT) {
      const u16* LAn = lds + ((kt + 1) & 1) * 32768;
      readA(a0, LAn, 0);
      readB(b0, LAn + 16384, 0);
    }
    __builtin_amdgcn_s_setprio(1);
#pragma unroll
    for (int kc = 0; kc < 2; ++kc)
#pragma unroll
      for (int i = 0; i < 4; ++i)
#pragma unroll
        for (int j = 0; j < 2; ++j)
          acc[4 + i][2 + j] = MFMA16(a1[kc][i], b1[kc][j], acc[4 + i][2 + j]);
    __builtin_amdgcn_s_setprio(0);
    __builtin_amdgcn_s_barrier();
  }

  // ---- epilogue: fp32 LDS bounce -> coalesced stores ----
  // Two halves of 128 rows. XOR key ((lr&3)^((lr>>2)&3))<<4 makes both the
  // writer (rows step 4 per quad) and reader (rows step 1 per quad)
  // bank-conflict-free; reader's 4-col groups stay contiguous under the XOR.
  float* fl = (float*)lds;   // 128 x 256 fp32 = 128 KiB
#pragma unroll 1
  for (int half = 0; half < 2; ++half) {
    __syncthreads();
    if (wm == half) {
#pragma unroll
      for (int ni = 0; ni < 4; ++ni) {
        float bv = bias[bn + wn * 64 + ni * 16 + l15];
#pragma unroll
        for (int mi = 0; mi < 8; ++mi) {
#pragma unroll
          for (int r = 0; r < 4; ++r) {
            int lr = mi * 16 + quad * 4 + r;
            int c  = wn * 64 + ni * 16 + l15;
            int key = ((r ^ quad) & 3) << 4;
            fl[lr * 256 + (c ^ key)] = acc[mi][ni][r] + bv;
          }
        }
      }
    }
    __syncthreads();
    // reader: wave w owns rows w*16..w*16+15; per (cc,rr) one 128B row-chunk
    // store per quad (16 lanes x ushort4).
#pragma unroll 1
    for (int cc = 0; cc < 4; ++cc) {
      int col0 = bn + cc * 64;
#pragma unroll
      for (int rr = 0; rr < 4; ++rr) {
        int lr = w * 16 + rr * 4 + quad;
        int key = ((rr ^ quad) & 3) << 4;
        float4 v = *(const float4*)&fl[lr * 256 + ((cc * 64 + (l15 << 2)) ^ key)];
        int grow = bm + half * 128 + lr;
        if (col0 < 3072) {
          ushort4 hv;
          hv.x = f2bf(v.x); hv.y = f2bf(v.y); hv.z = f2bf(v.z); hv.w = f2bf(v.w);
          int matsel = col0 >> 10;
          int hh2 = (col0 >> 6) & 15;
          if (grow < 4096) {
            int bb = grow >> 8, ss = grow & 255;
            *(ushort4*)(Cv + (size_t)matsel * 4194304 +
                        ((size_t)(((bb << 4) + hh2) << 8) + ss) * 64 + (l15 << 2)) = hv;
          } else if (matsel == 2) {      // table @ Wk^T -> RPKh
            int pp = grow - 4096;
            *(ushort4*)(Cv + (size_t)3 * 4194304 +
                        ((size_t)((hh2 << 8) + pp)) * 64 + (l15 << 2)) = hv;
          }
        } else if (col0 < 3104) {        // the 3072..3135 chunk: utb/dtb cols
#pragma unroll
          for (int e = 0; e < 4; ++e) {
            int col = col0 + (l15 << 2) + e;
            float vv = e == 0 ? v.x : e == 1 ? v.y : e == 2 ? v.z : v.w;
            if (col < 3088) {
              if (grow < 4096)
                utb[((grow >> 8) * 16 + (col - 3072)) * 256 + (grow & 255)] = vv;
            } else if (col < 3104) {
              if (grow >= 4096)
                dtb[(col - 3088) * 256 + (grow - 4096)] = vv;
            }
          }
        }
        // col0 >= 3136 (incl. N-pad): discarded
      }
    }
  }
}

// ---------------- fused attention: one block per (b,h), K/V in LDS ----------------
__global__ __launch_bounds__(512, 2) void attn_k(
    const u16* __restrict__ Qh, const u16* __restrict__ Kh,
    const u16* __restrict__ Vh, const u16* __restrict__ RPKh,
    const float* __restrict__ ut, const float* __restrict__ dt,
    u16* __restrict__ vw) {
  __shared__ u16 Klds[256 * 64];     // 32 KB, XOR-swizzled rows
  __shared__ u16 Vt[64][280];        // 35 KB, V transposed
  __shared__ float Sc[32][257];      // scores by z
  __shared__ float Sc2[32][257];     // rel scores by p
  __shared__ float Ut[256], Dt[256], Rinv[32];

  const int bh = blockIdx.x;         // b*16 + h
  const int h = bh & 15;
  const int b = bh >> 4;
  const size_t bh256 = (size_t)bh << 8;

  const int t = threadIdx.x, w = t >> 6, l = t & 63;
  const int l15 = l & 15, quad = l >> 4;

  // ---- staging: K (GLL16), V^T (LDS transpose), Ut, Dt ----
  {
    const int lrow8 = l >> 3, kslot = l & 7;
#pragma unroll
    for (int i = 0; i < 4; ++i) {
      int row = w * 32 + i * 8 + lrow8;
      int gk = (kslot ^ (row & 7)) << 3;
      GLL16(Kh + (bh256 + row) * 64 + gk, Klds + (w * 32 + i * 8) * 64);
    }
  }
  {
    int z = t & 255, dh = t >> 8;    // dh: 0..1 (wave-uniform)
    const u16* gp = Vh + (bh256 + z) * 64 + dh * 32;
    ushort4 vv[8];
#pragma unroll
    for (int i = 0; i < 8; ++i) vv[i] = *(const ushort4*)(gp + i * 4);
#pragma unroll
    for (int i = 0; i < 8; ++i) {
      Vt[dh * 32 + i * 4 + 0][z] = vv[i].x;
      Vt[dh * 32 + i * 4 + 1][z] = vv[i].y;
      Vt[dh * 32 + i * 4 + 2][z] = vv[i].z;
      Vt[dh * 32 + i * 4 + 3][z] = vv[i].w;
    }
  }
  if (t < 256) Ut[t] = ut[bh256 + t];
  else         Dt[t - 256] = dt[((size_t)h << 8) + (t - 256)];
  __syncthreads();

  // ---- loop over 8 s-tiles of 32 rows ----
  for (int st = 0; st < 8; ++st) {
    const int s0 = st * 32;

    bf16x8 qa[2][2];
#pragma unroll
    for (int rt = 0; rt < 2; ++rt) {
      const u16* qp = Qh + (bh256 + s0 + rt * 16 + l15) * 64 + quad * 8;
      qa[rt][0] = *(const bf16x8*)qp;
      qa[rt][1] = *(const bf16x8*)(qp + 32);
    }

    // merged QK (-> Sc) + QR (-> Sc2); tasks round-robin over 8 waves
    {
      int cnt = 0;
#pragma unroll
      for (int rt = 0; rt < 2; ++rt) {
        const int rB = s0 + rt * 16;
        const int nzt = 2 * st + rt + 1;
        for (int zt = 0; zt < nzt; ++zt, ++cnt) {
          if ((cnt & 7) != w) continue;  // wave-uniform
          const int zr = (zt << 4) + l15;
          const u16* krow = Klds + zr * 64;
          bf16x8 kb0 = *(const bf16x8*)(krow + ((quad ^ (zr & 7)) << 3));
          bf16x8 kb1 = *(const bf16x8*)(krow + (((quad + 4) ^ (zr & 7)) << 3));
          floatx4 acc = {};
          acc = MFMA16(qa[rt][0], kb0, acc);
          acc = MFMA16(qa[rt][1], kb1, acc);
          float u = Ut[zr];
#pragma unroll
          for (int r = 0; r < 4; ++r)
            Sc[rt * 16 + quad * 4 + r][zr] = acc[r] + u;
        }
        for (int j = 0; j < nzt; ++j, ++cnt) {
          if ((cnt & 7) != w) continue;
          const int pr = 240 - rB + (j << 4) + l15;
          const u16* rp = RPKh + ((size_t)(h << 8) + pr) * 64 + quad * 8;
          bf16x8 rb0 = *(const bf16x8*)rp;
          bf16x8 rb1 = *(const bf16x8*)(rp + 32);
          floatx4 acc = {};
          acc = MFMA16(qa[rt][0], rb0, acc);
          acc = MFMA16(qa[rt][1], rb1, acc);
          float dv = Dt[pr];
#pragma unroll
          for (int r = 0; r < 4; ++r)
            Sc2[rt * 16 + quad * 4 + r][pr] = acc[r] + dv;
        }
      }
    }
    __syncthreads();

    // softmax: 4 rows/wave, 16 lanes/row; P -> Sc
    {
      const int row = w * 4 + (l >> 4);
      const int c16 = l & 15;
      const int s = s0 + row;
      const int zfill = 32 * (st + 1);
      float m = -1e30f;
      for (int z = c16; z <= s; z += 16)
        m = fmaxf(m, Sc[row][z] + Sc2[row][z - s + 255]);
      m = fmaxf(m, __shfl_xor(m, 1));
      m = fmaxf(m, __shfl_xor(m, 2));
      m = fmaxf(m, __shfl_xor(m, 4));
      m = fmaxf(m, __shfl_xor(m, 8));
      m *= kScale;
      float sum = 0.f;
      for (int z = c16; z < zfill; z += 16) {
        float e = 0.f;
        if (z <= s) {
          e = __expf((Sc[row][z] + Sc2[row][z - s + 255]) * kScale - m);
          sum += e;
        }
        Sc[row][z] = e;
      }
      sum += __shfl_xor(sum, 1);
      sum += __shfl_xor(sum, 2);
      sum += __shfl_xor(sum, 4);
      sum += __shfl_xor(sum, 8);
      if (c16 == 0) Rinv[row] = 1.f / sum;
    }
    __syncthreads();

    // PV: wave = (strip = w>>2, nt = w&3); V from LDS
    {
      const int strip = w >> 2, nt = w & 3;
      const int sB = s0 + strip * 16;
      floatx4 oacc = {};
      for (int kc = 0; kc <= st; ++kc) {
        const float* prow = &Sc[strip * 16 + l15][kc * 32 + quad * 8];
        bf16x8 pa;
        pa[0] = (short)f2bf(prow[0]); pa[1] = (short)f2bf(prow[1]);
        pa[2] = (short)f2bf(prow[2]); pa[3] = (short)f2bf(prow[3]);
        pa[4] = (short)f2bf(prow[4]); pa[5] = (short)f2bf(prow[5]);
        pa[6] = (short)f2bf(prow[6]); pa[7] = (short)f2bf(prow[7]);
        const u16* vp = &Vt[nt * 16 + l15][kc * 32 + quad * 8];
        bf16x8 vbf = *(const bf16x8*)vp;
        oacc = MFMA16(pa, vbf, oacc);
      }
#pragma unroll
      for (int r = 0; r < 4; ++r) {
        float ivr = Rinv[strip * 16 + quad * 4 + r];
        int srow = sB + quad * 4 + r;
        vw[(size_t)(b * 256 + srow) * 1024 + h * 64 + nt * 16 + l15] =
            f2bf(oacc[r] * ivr);
      }
    }
    __syncthreads();
  }
}

extern "C" void kernel_launch(void* const* d_in, const int* in_sizes, int n_in,
                              void* d_out, int out_size, void* d_ws, size_t ws_size,
                              hipStream_t stream) {
  const float* x  = (const float*)d_in[0];
  const float* Wq = (const float*)d_in[1];
  const float* bq = (const float*)d_in[2];
  const float* Wk = (const float*)d_in[3];
  const float* bk = (const float*)d_in[4];
  const float* Wv = (const float*)d_in[5];
  const float* bv = (const float*)d_in[6];
  const float* Wr = (const float*)d_in[7];
  const float* br = (const float*)d_in[8];
  const float* ub = (const float*)d_in[9];
  const float* vb = (const float*)d_in[10];
  const float* Wo = (const float*)d_in[11];
  const float* bo = (const float*)d_in[12];
  float* out = (float*)d_out;

  char* base = (char*)d_ws;
  size_t off = 0;
  auto alloc = [&](size_t bytes) {
    void* p = base + off;
    off += (bytes + 255) & ~(size_t)255;
    return p;
  };

  const size_t MAT = (size_t)4194304;  // 4096*1024
  u16*   xA    = (u16*)alloc((size_t)4352 * 1024 * 2);       // [x ; table]
  u16*   W3b   = (u16*)alloc((size_t)3328 * 1024 * 2);       // [Wq;Wv;Wk;UV;pad to 13 n-tiles]
  u16*   Wob   = (u16*)alloc((size_t)1024 * 1024 * 2);
  float* b3    = (float*)alloc((size_t)3328 * 4);            // [bq;bv;bk;ub.br;vb.br;0;pad]
  u16*   Ph    = (u16*)alloc((3 * MAT + 262144) * 2);        // Qh,Vh,Kh,RPKh
  float* utb   = (float*)alloc((size_t)65536 * 4);
  float* dtb   = (float*)alloc((size_t)4096 * 4);
  u16*   vwb   = (u16*)alloc((size_t)4096 * 1024 * 2);

  u16* Qh   = Ph;
  u16* Vh   = Ph + MAT;
  u16* Kh   = Ph + 2 * MAT;
  u16* RPKh = Ph + 3 * MAT;

  // pack + table: (4194304 + 4194304 + 3072 + 262144)/1024 = 8451 blocks
  pack_k<<<dim3(8451), dim3(256), 0, stream>>>(x, Wq, Wk, Wv, Wo, bq, bk, bv,
                                               xA, W3b, Wob, b3);
  // rank-16 fold of Wr with u/v biases -> W3b rows 3072.., b3 tail
  uv_fold_k<<<dim3(128), dim3(256), 0, stream>>>(Wr, br, ub, vb, W3b, b3);

  // fused Q|V|K + relpos-K + ut/dt projections: 4352 x 3328(pad) x 1024
  // 256^2 8-phase kernel; mTiles=17, nTiles=13 -> exactly 221 blocks,
  // bijective XCD swizzle (27-28 blocks/XCD, single round per CU).
  gemm256_k<<<dim3(221), dim3(512), 0, stream>>>(xA, W3b, b3, Ph,
                                                 1024, utb, dtb, 17, 13);

  // fused attention: one block per (b,h)
  attn_k<<<dim3(256), dim3(512), 0, stream>>>(Qh, Kh, Vh, RPKh, utb, dtb, vwb);

  // output projection: 4096 x 1024 x 1024, fp32 out; mTiles=32, nTiles=8 -> 256
  gemm_k<0><<<dim3(256), dim3(256), 0, stream>>>(vwb, Wob, bo, out,
                                                 4096, 1024, 1024, nullptr, nullptr,
                                                 32, 8);
}